// Round 9
// baseline (274.923 us; speedup 1.0000x reference)
//
#include <hip/hip_runtime.h>

typedef short short8 __attribute__((ext_vector_type(8)));
typedef float f32x4 __attribute__((ext_vector_type(4)));

#define H_ 384
#define W_ 384
#define C_ 32
#define HW_ 147456          // H_*W_
#define HP1F 385.0f         // (H+2*pad)-1 as float
#define NB 2                // pixel batches per wave

__device__ __forceinline__ unsigned short f2bf(float f) {
  unsigned int u = __float_as_uint(f);
  u += 0x7fffu + ((u >> 16) & 1u);   // RNE
  return (unsigned short)(u >> 16);
}

// Pack B (kernel) into MFMA-B-layout bf16 fragments in global scratch:
// entry e = (f-tile nt, k-step kk, lane ln): 8 bf16 = 16 B.
__global__ void prep_b_kernel(const float* __restrict__ kern, uint4* __restrict__ ws) {
  for (int e = threadIdx.x; e < 1152; e += 256) {
    const int ln = e & 63;
    const int kk = (e >> 6) % 9;
    const int nt = e / 576;
    const int f = nt * 16 + (ln & 15);
    const int q2 = ln >> 4;
    unsigned short rr[8];
#pragma unroll
    for (int i2 = 0; i2 < 8; ++i2)
      rr[i2] = f2bf(kern[(kk * 32 + q2 * 8 + i2) * 32 + f]);
    uint4 w;
    w.x = rr[0] | ((unsigned)rr[1] << 16);
    w.y = rr[2] | ((unsigned)rr[3] << 16);
    w.z = rr[4] | ((unsigned)rr[5] << 16);
    w.w = rr[6] | ((unsigned)rr[7] << 16);
    ws[e] = w;
  }
}

struct Tap {
  float w00, w01, w10, w11;
  float4 p00a, p00b, p01a, p01b, p10a, p10b, p11a, p11b;
  short8 bf0, bf1;
};

// Main kernel: NO LDS, NO barriers. Lane L gathers its own MFMA A-fragment
// (pixel L&15, channels (L>>4)*8..+7). B fragments stream from ws (L2-hot
// 18.4 KB broadcast). Explicit 2-deep software pipeline: issue(kk+1)'s ~10
// loads are in flight while consume(kk) does bilinear + MFMA.
__global__ __launch_bounds__(256, 3) void deform_conv_kernel(
    const float* __restrict__ x, const float* __restrict__ off,
    const short8* __restrict__ bws, const float* __restrict__ bias,
    float* __restrict__ out) {
  const int tid = threadIdx.x;
  const int lane = tid & 63;
  const int wv = tid >> 6;

  const int px = lane & 15;         // pixel within 16-tile == MFMA A row
  const int qq = lane >> 4;         // MFMA quad; channels qq*8..qq*8+7
  const int cb = qq * 8;            // first channel this lane owns

  const float bias0 = bias[px];
  const float bias1 = bias[16 + px];

  // XCD-aware swizzle (R2-verified: FETCH 170->30 MB). Bijection over
  // [0,2304): blk=8q+r -> 288r+q gives each XCD 96 contiguous image rows.
  const int lb = (blockIdx.x & 7) * 288 + (blockIdx.x >> 3);

  for (int nb = 0; nb < NB; ++nb) {
    const int g = lb * (4 * NB) + nb * 4 + wv;           // wave-group index
    const int P0 = g << 4;                               // first of 16 pixels
    const int b = (P0 >= HW_) ? 1 : 0;
    const int rem = P0 - b * HW_;
    const int i = rem / W_;
    const int j0 = rem - i * W_;     // group never crosses a row (W%16==0)
    const int j = j0 + px;

    // ---- prefetch all 9 offsets: 18 contiguous floats per pixel,
    // 9 independent 8B loads, all in flight before tap 0's chain starts ----
    const float2* ob = (const float2*)(off + (size_t)(i * W_ + j) * 18);
    const float2 o0 = ob[0], o1 = ob[1], o2 = ob[2], o3 = ob[3], o4 = ob[4],
                 o5 = ob[5], o6 = ob[6], o7 = ob[7], o8 = ob[8];

    f32x4 acc0 = {bias0, bias0, bias0, bias0};
    f32x4 acc1 = {bias1, bias1, bias1, bias1};

    auto issue = [&](int kk, float2 o) -> Tap {
      Tap t;
      const int di = kk / 3;          // kk is a literal at every callsite
      const int dj = kk - di * 3;
      float yf = (float)(i + di) + o.y;   // padded coords; o.y = y_off
      float xf = (float)(j + dj) + o.x;   // o.x = x_off
      yf = fminf(fmaxf(yf, 0.f), HP1F);
      xf = fminf(fmaxf(xf, 0.f), HP1F);
      const float y0f = floorf(yf);
      const float x0f = floorf(xf);
      const int y0 = (int)y0f;
      const int x0 = (int)x0f;
      // Fast path: all 4 corners strictly in-image; wave-uniform via __all.
      const int fast = ((unsigned)(y0 - 1) < 383u) & ((unsigned)(x0 - 1) < 383u);
      if (__all(fast)) {
        const float wy1 = yf - y0f;
        const float wy0 = (y0f + 1.0f) - yf;   // == (float)y1 - yf, y1=y0+1
        const float wx1 = xf - x0f;
        const float wx0 = (x0f + 1.0f) - xf;
        t.w00 = wy0 * wx0; t.w01 = wy0 * wx1;
        t.w10 = wy1 * wx0; t.w11 = wy1 * wx1;
        const int base00 = ((b * H_ + (y0 - 1)) * W_ + (x0 - 1)) * C_ + cb;
        // 8 unconditional independent 16B loads -> all in flight together
        t.p00a = *(const float4*)(x + base00);
        t.p00b = *(const float4*)(x + base00 + 4);
        t.p01a = *(const float4*)(x + base00 + C_);
        t.p01b = *(const float4*)(x + base00 + C_ + 4);
        t.p10a = *(const float4*)(x + base00 + W_ * C_);
        t.p10b = *(const float4*)(x + base00 + W_ * C_ + 4);
        t.p11a = *(const float4*)(x + base00 + W_ * C_ + C_);
        t.p11b = *(const float4*)(x + base00 + W_ * C_ + C_ + 4);
      } else {
        // Slow path: R0-style guarded loads (pad corners -> 0), 8 channels.
        const int y1 = min(y0 + 1, 385);
        const int x1 = min(x0 + 1, 385);
        const float wy1 = yf - y0f;
        const float wy0 = (float)y1 - yf;
        const float wx1 = xf - x0f;
        const float wx0 = (float)x1 - xf;
        t.w00 = wy0 * wx0; t.w01 = wy0 * wx1;
        t.w10 = wy1 * wx0; t.w11 = wy1 * wx1;
        const int yu0 = y0 - 1, xu0 = x0 - 1;
        const bool vy0 = (unsigned)yu0 < 384u, vy1 = (unsigned)(y1 - 1) < 384u;
        const bool vx0 = (unsigned)xu0 < 384u, vx1 = (unsigned)(x1 - 1) < 384u;
        const int base00 = ((b * H_ + yu0) * W_ + xu0) * C_ + cb;
        const int ddx = (x1 - x0) * C_;
        const int ddy = (y1 - y0) * (W_ * C_);
        t.p00a = {0,0,0,0}; t.p00b = {0,0,0,0};
        t.p01a = {0,0,0,0}; t.p01b = {0,0,0,0};
        t.p10a = {0,0,0,0}; t.p10b = {0,0,0,0};
        t.p11a = {0,0,0,0}; t.p11b = {0,0,0,0};
        if (vy0 && vx0) { t.p00a = *(const float4*)(x + base00);
                          t.p00b = *(const float4*)(x + base00 + 4); }
        if (vy0 && vx1) { t.p01a = *(const float4*)(x + base00 + ddx);
                          t.p01b = *(const float4*)(x + base00 + ddx + 4); }
        if (vy1 && vx0) { t.p10a = *(const float4*)(x + base00 + ddy);
                          t.p10b = *(const float4*)(x + base00 + ddy + 4); }
        if (vy1 && vx1) { t.p11a = *(const float4*)(x + base00 + ddy + ddx);
                          t.p11b = *(const float4*)(x + base00 + ddy + ddx + 4); }
      }
      // B fragments for this k-step: 2 independent 16B loads (L2-hot 18.4 KB)
      t.bf0 = bws[kk * 64 + lane];
      t.bf1 = bws[(9 + kk) * 64 + lane];
      return t;
    };

    auto consume = [&](const Tap& t) {
      const float v0 = t.w00*t.p00a.x + t.w01*t.p01a.x + t.w10*t.p10a.x + t.w11*t.p11a.x;
      const float v1 = t.w00*t.p00a.y + t.w01*t.p01a.y + t.w10*t.p10a.y + t.w11*t.p11a.y;
      const float v2 = t.w00*t.p00a.z + t.w01*t.p01a.z + t.w10*t.p10a.z + t.w11*t.p11a.z;
      const float v3 = t.w00*t.p00a.w + t.w01*t.p01a.w + t.w10*t.p10a.w + t.w11*t.p11a.w;
      const float v4 = t.w00*t.p00b.x + t.w01*t.p01b.x + t.w10*t.p10b.x + t.w11*t.p11b.x;
      const float v5 = t.w00*t.p00b.y + t.w01*t.p01b.y + t.w10*t.p10b.y + t.w11*t.p11b.y;
      const float v6 = t.w00*t.p00b.z + t.w01*t.p01b.z + t.w10*t.p10b.z + t.w11*t.p11b.z;
      const float v7 = t.w00*t.p00b.w + t.w01*t.p01b.w + t.w10*t.p10b.w + t.w11*t.p11b.w;
      uint4 aw;
      aw.x = f2bf(v0) | ((unsigned)f2bf(v1) << 16);
      aw.y = f2bf(v2) | ((unsigned)f2bf(v3) << 16);
      aw.z = f2bf(v4) | ((unsigned)f2bf(v5) << 16);
      aw.w = f2bf(v6) | ((unsigned)f2bf(v7) << 16);
      const short8 af = __builtin_bit_cast(short8, aw);
      acc0 = __builtin_amdgcn_mfma_f32_16x16x32_bf16(af, t.bf0, acc0, 0, 0, 0);
      acc1 = __builtin_amdgcn_mfma_f32_16x16x32_bf16(af, t.bf1, acc1, 0, 0, 0);
    };

    // ---- explicit 2-deep pipeline; consume order kk = 0..8 (acc order
    // identical to R5/R7 -> bit-identical output) ----
    Tap tA = issue(0, o0);
    Tap tB = issue(1, o1);
    consume(tA);  tA = issue(2, o2);
    consume(tB);  tB = issue(3, o3);
    consume(tA);  tA = issue(4, o4);
    consume(tB);  tB = issue(5, o5);
    consume(tA);  tA = issue(6, o6);
    consume(tB);  tB = issue(7, o7);
    consume(tA);  tA = issue(8, o8);
    consume(tB);
    consume(tA);

    // D layout: col = lane&15, row = qq*4 + reg
    float* op = out + (size_t)(P0 + qq * 4) * 32 + px;
#pragma unroll
    for (int r = 0; r < 4; ++r) {
      op[r * 32] = acc0[r];
      op[r * 32 + 16] = acc1[r];
    }
  }
}

extern "C" void kernel_launch(void* const* d_in, const int* in_sizes, int n_in,
                              void* d_out, int out_size, void* d_ws, size_t ws_size,
                              hipStream_t stream) {
  const float* x    = (const float*)d_in[0];
  const float* off  = (const float*)d_in[1];
  const float* kern = (const float*)d_in[2];
  const float* bias = (const float*)d_in[3];
  float* out = (float*)d_out;
  // Pack B into scratch (18.4 KB), then main. Same stream -> ordered.
  prep_b_kernel<<<dim3(1), dim3(256), 0, stream>>>(kern, (uint4*)d_ws);
  deform_conv_kernel<<<dim3(2304), dim3(256), 0, stream>>>(
      x, off, (const short8*)d_ws, bias, out);
}